// Round 1
// baseline (300.788 us; speedup 1.0000x reference)
//
#include <hip/hip_runtime.h>

// MatrixFactorization: out[i] = dot(user_i, item_table[dest_i])
// user_i = b + sum_k emb_k[idx_k[i]] @ W_k  (W_k = rows [4k,4k+4) of W[24,32])
// Precompute proj_k[v][f] = sum_d emb_k[v][d]*W[4k+d][f] (+b for k=0) into LDS.

#define NF 32
#define LDS_STRIDE 36           // floats per padded table row (144 B, 16B-aligned, breaks bank alignment)
#define NV 176                  // 7+24+2+100+12+31 vocab entries

__global__ __launch_bounds__(256)
void mf_kernel(const int* __restrict__ dow, const int* __restrict__ tmi,
               const int* __restrict__ sx,  const int* __restrict__ ag,
               const int* __restrict__ mo,  const int* __restrict__ dy,
               const int* __restrict__ dst,
               const float* __restrict__ e_dow,   const float* __restrict__ e_time,
               const float* __restrict__ e_sex,   const float* __restrict__ e_age,
               const float* __restrict__ e_month, const float* __restrict__ e_day,
               const float* __restrict__ W, const float* __restrict__ bvec,
               const float* __restrict__ item_table,
               float* __restrict__ out, int n)
{
    __shared__ float proj[NV * LDS_STRIDE];   // 25,344 B

    // ---- Stage 1: build projected vocab tables in LDS ----
    // entry ranges: dow [0,7) time [7,31) sex [31,33) age [33,133) month [133,145) day [145,176)
    const int tid = threadIdx.x;
    for (int t = tid; t < NV * NF; t += blockDim.x) {
        int entry = t >> 5;
        int f     = t & 31;
        int k, v;
        const float* e;
        if      (entry < 7)   { k = 0; v = entry;       e = e_dow;   }
        else if (entry < 31)  { k = 1; v = entry - 7;   e = e_time;  }
        else if (entry < 33)  { k = 2; v = entry - 31;  e = e_sex;   }
        else if (entry < 133) { k = 3; v = entry - 33;  e = e_age;   }
        else if (entry < 145) { k = 4; v = entry - 133; e = e_month; }
        else                  { k = 5; v = entry - 145; e = e_day;   }
        float acc = (k == 0) ? bvec[f] : 0.0f;
        #pragma unroll
        for (int d = 0; d < 4; ++d)
            acc += e[v * 4 + d] * W[(k * 4 + d) * NF + f];
        proj[entry * LDS_STRIDE + f] = acc;
    }
    __syncthreads();

    // ---- Stage 2: grid-stride over rows ----
    const int gstride = gridDim.x * blockDim.x;
    for (int i = blockIdx.x * blockDim.x + tid; i < n; i += gstride) {
        const int b0 = (0   + dow[i]) * LDS_STRIDE;
        const int b1 = (7   + tmi[i]) * LDS_STRIDE;
        const int b2 = (31  + sx[i])  * LDS_STRIDE;
        const int b3 = (33  + ag[i])  * LDS_STRIDE;
        const int b4 = (133 + mo[i])  * LDS_STRIDE;
        const int b5 = (145 + dy[i])  * LDS_STRIDE;
        const float4* it = reinterpret_cast<const float4*>(item_table + (long long)dst[i] * NF);
        float acc = 0.0f;
        #pragma unroll
        for (int q = 0; q < 8; ++q) {
            float4 iv = it[q];
            float4 u0 = *reinterpret_cast<const float4*>(&proj[b0 + q * 4]);
            float4 u1 = *reinterpret_cast<const float4*>(&proj[b1 + q * 4]);
            float4 u2 = *reinterpret_cast<const float4*>(&proj[b2 + q * 4]);
            float4 u3 = *reinterpret_cast<const float4*>(&proj[b3 + q * 4]);
            float4 u4 = *reinterpret_cast<const float4*>(&proj[b4 + q * 4]);
            float4 u5 = *reinterpret_cast<const float4*>(&proj[b5 + q * 4]);
            float ux = u0.x + u1.x + u2.x + u3.x + u4.x + u5.x;
            float uy = u0.y + u1.y + u2.y + u3.y + u4.y + u5.y;
            float uz = u0.z + u1.z + u2.z + u3.z + u4.z + u5.z;
            float uw = u0.w + u1.w + u2.w + u3.w + u4.w + u5.w;
            acc += ux * iv.x + uy * iv.y + uz * iv.z + uw * iv.w;
        }
        out[i] = acc;
    }
}

extern "C" void kernel_launch(void* const* d_in, const int* in_sizes, int n_in,
                              void* d_out, int out_size, void* d_ws, size_t ws_size,
                              hipStream_t stream) {
    const int* dow = (const int*)d_in[0];
    const int* tmi = (const int*)d_in[1];
    const int* sx  = (const int*)d_in[2];
    const int* ag  = (const int*)d_in[3];
    const int* mo  = (const int*)d_in[4];
    const int* dy  = (const int*)d_in[5];
    const int* dst = (const int*)d_in[6];
    const float* e_dow   = (const float*)d_in[7];
    const float* e_time  = (const float*)d_in[8];
    const float* e_sex   = (const float*)d_in[9];
    const float* e_age   = (const float*)d_in[10];
    const float* e_month = (const float*)d_in[11];
    const float* e_day   = (const float*)d_in[12];
    const float* W       = (const float*)d_in[13];
    const float* bvec    = (const float*)d_in[14];
    const float* item    = (const float*)d_in[15];
    float* out = (float*)d_out;
    const int n = in_sizes[0];

    dim3 grid(2048), block(256);
    mf_kernel<<<grid, block, 0, stream>>>(dow, tmi, sx, ag, mo, dy, dst,
                                          e_dow, e_time, e_sex, e_age, e_month, e_day,
                                          W, bvec, item, out, n);
}